// Round 6
// baseline (40.514 us; speedup 1.0000x reference)
//
#include <hip/hip_runtime.h>
#include <math.h>

// Voxelized chamfer via bf16 MFMA, single-P formulation:
//   vox coords are integer-valued fp32 in ~[-100, 150] -> EXACT in bf16.
//   d[i][j] = pred_i . gt_j via mfma_f32_16x16x32_bf16 (K padded 3->32,
//   zeros): products <= ~40k, sums < 2^24 -> fp32-exact.
//   P = xx_i + yy_j - 2 d  (exact integers) ; loss = mean row-min + col-min.
//
// k1: 512 blocks = (batch, 32-pred-row tile). Stage: voxelize all 4096 gt
//     (packed bf16 {x,y,z,0} + fp32 yy) and the block's 32 preds into LDS
//     (ALL IEEE divides here, bit-identical to reference). Each of 4 waves
//     owns 64 gt col-tiles of 16. Per tile: 1 LDS b64 broadcast (B-frag),
//     2 MFMA (two 16-row tiles), epilogue e=fma(d,-2,yy) -> row-min regs,
//     P=e+xx -> col-min fold (7 min + 2 shfl) -> exec-masked 64 B store to
//     colPart. Row-mins: 4-level shfl + LDS cross-wave -> rowPart[bid].
// k2: (unchanged, proven) min-combine colPart over the 128 row tiles, fold
//     rowPart, atomicAdd exact multiples of 2^-14 (order-independent).

typedef float  f32x4  __attribute__((ext_vector_type(4)));
typedef short  bf16x8 __attribute__((ext_vector_type(8)));

constexpr int NPTS  = 4096;
constexpr int BLK   = 256;
constexpr int QPB   = 32;             // pred rows per block
constexpr int NRB   = NPTS / QPB;     // 128 row tiles per batch
constexpr int BATCH = 4;
constexpr float FINF  = 3.402823466e38f;
constexpr float SCALE = 1.0f / 16384.0f;   // 1/(B*N) = 2^-14, exact

__device__ __forceinline__ float vox(float c, float off) {
    return truncf((c + off) / 0.05f);  // IEEE div: bit-matches reference
}
__device__ __forceinline__ unsigned bfbits(float v) {
    return __float_as_uint(v) >> 16;   // exact: integer-valued |v| <= 256
}

__global__ __launch_bounds__(BLK) void chamfer_tile_kernel(
    const float* __restrict__ preds,
    const float* __restrict__ gts,
    float* __restrict__ colPart,   // [BATCH*NRB][NPTS]
    float* __restrict__ rowPart,   // [BATCH*NRB]
    float* __restrict__ out)
{
    __shared__ uint2 gpack[NPTS];       // gt {x,y bf16 | z,0 bf16}
    __shared__ float gyy[NPTS];         // gt squared norms (exact ints)
    __shared__ uint2 ppack[QPB];        // pred packed
    __shared__ float pxx[QPB];          // pred squared norms
    __shared__ float waveRow[4][QPB];   // cross-wave row-min combine

    const int t    = threadIdx.x;
    const int bid  = blockIdx.x;
    const int b    = bid / NRB;
    const int rb   = bid - b * NRB;
    const int w    = t >> 6;
    const int lane = t & 63;

    if (bid == 0 && t == 0) out[0] = 0.0f;     // k2's accumulator

    const float* __restrict__ pb = preds + (size_t)b * NPTS * 3;
    const float* __restrict__ gb = gts   + (size_t)b * NPTS * 3;

    // ---- stage gt: voxelize, pack bf16, norms ----
    for (int j = t; j < NPTS; j += BLK) {
        const float x = vox(gb[j*3+0], 3.0f);
        const float y = vox(gb[j*3+1], 3.0f);
        const float z = vox(gb[j*3+2], 1.0f);
        gpack[j] = make_uint2((__float_as_uint(y) & 0xFFFF0000u) | bfbits(x),
                              bfbits(z));
        gyy[j]   = fmaf(z, z, fmaf(y, y, x * x));
    }
    // ---- stage the block's 32 pred rows ----
    if (t < QPB) {
        const int qi = rb * QPB + t;
        const float x = vox(pb[qi*3+0], 3.0f);
        const float y = vox(pb[qi*3+1], 3.0f);
        const float z = vox(pb[qi*3+2], 1.0f);
        ppack[t] = make_uint2((__float_as_uint(y) & 0xFFFF0000u) | bfbits(x),
                              bfbits(z));
        pxx[t]   = fmaf(z, z, fmaf(y, y, x * x));
    }
    __syncthreads();

    const int lq  = lane & 15;          // col / row within 16-tile
    const int grp = lane >> 4;          // lane group 0..3
    const bool lo = (grp == 0);         // k=0..7 carrier group

    // A fragments for the two 16-row pred tiles (row = lq for group 0).
    bf16x8 afrag[2];
    float  xxf[2][4];
    #pragma unroll
    for (int rt = 0; rt < 2; ++rt) {
        const uint2 pw = ppack[rt * 16 + lq];
        int4 ai = { lo ? (int)pw.x : 0, lo ? (int)pw.y : 0, 0, 0 };
        afrag[rt] = __builtin_bit_cast(bf16x8, ai);
        #pragma unroll
        for (int i = 0; i < 4; ++i)
            xxf[rt][i] = pxx[rt * 16 + grp * 4 + i];
    }

    f32x4 rm[2];
    rm[0] = (f32x4){FINF, FINF, FINF, FINF};
    rm[1] = (f32x4){FINF, FINF, FINF, FINF};
    const f32x4 zero = (f32x4){0.f, 0.f, 0.f, 0.f};
    float* __restrict__ colDst = colPart + (size_t)bid * NPTS;

    #pragma unroll 4
    for (int jt = w * 64; jt < w * 64 + 64; ++jt) {
        const int j = jt * 16 + lq;
        const uint2 gw = gpack[j];           // broadcast across 4 groups
        const float yv = gyy[j];
        int4 bi = { lo ? (int)gw.x : 0, lo ? (int)gw.y : 0, 0, 0 };
        const bf16x8 bfrag = __builtin_bit_cast(bf16x8, bi);

        const f32x4 d0 = __builtin_amdgcn_mfma_f32_16x16x32_bf16(
            afrag[0], bfrag, zero, 0, 0, 0);
        const f32x4 d1 = __builtin_amdgcn_mfma_f32_16x16x32_bf16(
            afrag[1], bfrag, zero, 0, 0, 0);

        float P[8];
        #pragma unroll
        for (int i = 0; i < 4; ++i) {
            const float e0 = fmaf(d0[i], -2.0f, yv);   // yy - 2d (exact)
            rm[0][i] = fminf(rm[0][i], e0);
            P[i]     = e0 + xxf[0][i];
            const float e1 = fmaf(d1[i], -2.0f, yv);
            rm[1][i] = fminf(rm[1][i], e1);
            P[4 + i] = e1 + xxf[1][i];
        }
        // col-min over this block's 32 pred rows for col j
        float cm = fminf(fminf(fminf(P[0], P[1]), fminf(P[2], P[3])),
                         fminf(fminf(P[4], P[5]), fminf(P[6], P[7])));
        cm = fminf(cm, __shfl_xor(cm, 16, 64));
        cm = fminf(cm, __shfl_xor(cm, 32, 64));
        if (lane < 16) colDst[j] = cm;       // 64 B coalesced, write-once
    }

    // ---- row-min wrap-up: min over the 16 cols held across lq lanes ----
    #pragma unroll
    for (int rt = 0; rt < 2; ++rt) {
        #pragma unroll
        for (int i = 0; i < 4; ++i) {
            float v = rm[rt][i];
            v = fminf(v, __shfl_xor(v, 1, 64));
            v = fminf(v, __shfl_xor(v, 2, 64));
            v = fminf(v, __shfl_xor(v, 4, 64));
            v = fminf(v, __shfl_xor(v, 8, 64));
            if (lq == 0)                     // one writer per (grp, rt, i)
                waveRow[w][rt * 16 + grp * 4 + i] = v + xxf[rt][i];
        }
    }
    __syncthreads();

    if (w == 0) {                            // combine waves + exact int sum
        float s = 0.0f;
        if (lane < QPB) {
            s = fminf(fminf(waveRow[0][lane], waveRow[1][lane]),
                      fminf(waveRow[2][lane], waveRow[3][lane]));
        }
        #pragma unroll
        for (int o = 32; o >= 1; o >>= 1) s += __shfl_xor(s, o, 64);
        if (lane == 0) rowPart[bid] = s;
    }
}

// ---------------- k2: column-min combine + final sum (unchanged) ----------
__global__ __launch_bounds__(BLK) void chamfer_finish_kernel(
    const float* __restrict__ colPart,
    const float* __restrict__ rowPart,
    float* __restrict__ out)
{
    __shared__ float red[8][QPB];
    __shared__ float s1[BLK];

    const int t  = threadIdx.x;
    const int g  = blockIdx.x;            // 512 blocks: (b, 32-j tile)
    const int b  = g >> 7;
    const int jt = g & 127;
    const int rbg = t >> 5, jo = t & 31;
    const int j = jt * QPB + jo;

    const float* __restrict__ col = colPart + (size_t)(b * NRB) * NPTS + j;
    float cm = FINF;
    #pragma unroll
    for (int r = 0; r < 16; ++r)
        cm = fminf(cm, col[(size_t)(rbg * 16 + r) * NPTS]);
    red[rbg][jo] = cm;
    __syncthreads();

    float v = 0.0f;
    if (t < 32) {
        float m = red[0][t];
        #pragma unroll
        for (int r2 = 1; r2 < 8; ++r2) m = fminf(m, red[r2][t]);
        v = m;                            // final col-min for query-col j
    }
    if (g == 0) v += rowPart[t] + rowPart[t + 256];   // fold dist1 once
    s1[t] = v;
    __syncthreads();
    for (int k = 128; k > 0; k >>= 1) {
        if (t < k) s1[t] += s1[t + k];
        __syncthreads();
    }
    if (t == 0) atomicAdd(out, s1[0] * SCALE);   // exact multiple of 2^-14
}

extern "C" void kernel_launch(void* const* d_in, const int* in_sizes, int n_in,
                              void* d_out, int out_size, void* d_ws, size_t ws_size,
                              hipStream_t stream)
{
    const float* preds = (const float*)d_in[0];
    const float* gts   = (const float*)d_in[1];
    float* out = (float*)d_out;

    float* colPart = (float*)d_ws;                               // 8 MB
    float* rowPart = colPart + (size_t)BATCH * NRB * NPTS;       // 2 KB

    chamfer_tile_kernel<<<BATCH * NRB, BLK, 0, stream>>>(
        preds, gts, colPart, rowPart, out);
    chamfer_finish_kernel<<<BATCH * NPTS / QPB, BLK, 0, stream>>>(
        colPart, rowPart, out);
}

// Round 7
// 29.747 us; speedup vs baseline: 1.3620x; 1.3620x over previous
//
#include <hip/hip_runtime.h>
#include <math.h>

// Voxelized chamfer via bf16 MFMA, direction-parallel, zero intermediates:
//   vox coords are integer-valued fp32, |v| <= ~160 -> EXACT in bf16.
//   d[i][j] = q_i . c_j via mfma_f32_16x16x32_bf16 (K padded 3->32): all
//   products/sums < 2^24 -> fp32-exact. P = xx + (yy - 2d), exact integers.
//   loss = mean(row-mins, pred->gt) + mean(row-mins, gt->pred).
//
// k1: 512 blocks = (dir, batch, 64-query tile). Stage the full candidate
//     cloud voxelized in LDS (packed bf16 {x,y,z,0} uint2 + fp32 norm; all
//     IEEE divides here, bit-identical to reference). Each of 4 waves scans
//     64 col-tiles of 16: 1 ds_read_b64 + 1 ds_read_b32 broadcast, 4 MFMA
//     (four 16-row query tiles), 16 fma + 16 min epilogue into registers.
//     No per-iter shuffles/stores. B-frag needs NO zero-masking: A-frag
//     k-slots 8..31 are +0.0, and 0 x finite = 0 exactly.
//     Row-mins: 4-level shfl min (across the 16 cols in lanes) -> +xx ->
//     cross-wave LDS min -> exact int sum -> partials[bid]. ONE float/block.
// k2: 1 block sums 512 partials (fixed-order tree, exact) and OVERWRITES
//     out[0] = sum * 2^-14 -> no init dispatch, no atomics, deterministic.

typedef float  f32x4  __attribute__((ext_vector_type(4)));
typedef short  bf16x8 __attribute__((ext_vector_type(8)));

constexpr int NPTS  = 4096;
constexpr int BLK   = 256;
constexpr int QPB   = 64;             // query rows per block
constexpr int NTB   = NPTS / QPB;     // 64 row tiles per (dir, batch)
constexpr int BATCH = 4;
constexpr float FINF  = 3.402823466e38f;
constexpr float SCALE = 1.0f / 16384.0f;   // 1/(B*N) = 2^-14, exact

__device__ __forceinline__ float vox(float c, float off) {
    return truncf((c + off) / 0.05f);  // IEEE div: bit-matches reference
}
__device__ __forceinline__ unsigned bfbits(float v) {
    return __float_as_uint(v) >> 16;   // exact: integer-valued |v| <= 256
}

__global__ __launch_bounds__(BLK) void chamfer_rows_kernel(
    const float* __restrict__ preds,
    const float* __restrict__ gts,
    float* __restrict__ partials)      // [512]
{
    __shared__ uint2 cpack[NPTS];       // candidates {x,y | z,0} bf16
    __shared__ float cyy[NPTS];         // candidate squared norms (exact)
    __shared__ uint2 qpack[QPB];        // this block's queries
    __shared__ float qxx[QPB];
    __shared__ float waveRow[4][QPB];

    const int t    = threadIdx.x;
    const int bid  = blockIdx.x;        // dir*256 + b*64 + tile
    const int dir  = bid >> 8;
    const int rem  = bid & 255;
    const int b    = rem >> 6;
    const int tile = rem & 63;
    const int w    = t >> 6;
    const int lane = t & 63;

    const float* __restrict__ xb = (dir ? gts : preds) + (size_t)b * NPTS * 3;
    const float* __restrict__ yb = (dir ? preds : gts) + (size_t)b * NPTS * 3;

    // ---- stage candidates: voxelize, pack bf16, norms ----
    for (int j = t; j < NPTS; j += BLK) {
        const float x = vox(yb[j*3+0], 3.0f);
        const float y = vox(yb[j*3+1], 3.0f);
        const float z = vox(yb[j*3+2], 1.0f);
        cpack[j] = make_uint2((__float_as_uint(y) & 0xFFFF0000u) | bfbits(x),
                              bfbits(z));
        cyy[j]   = fmaf(z, z, fmaf(y, y, x * x));
    }
    // ---- stage this block's 64 query rows ----
    if (t < QPB) {
        const int qi = tile * QPB + t;
        const float x = vox(xb[qi*3+0], 3.0f);
        const float y = vox(xb[qi*3+1], 3.0f);
        const float z = vox(xb[qi*3+2], 1.0f);
        qpack[t] = make_uint2((__float_as_uint(y) & 0xFFFF0000u) | bfbits(x),
                              bfbits(z));
        qxx[t]   = fmaf(z, z, fmaf(y, y, x * x));
    }
    __syncthreads();

    const int lq  = lane & 15;          // row (A) / col (B) within 16-tile
    const int grp = lane >> 4;          // lane group 0..3
    const bool lo = (grp == 0);         // k=0..7 carrier group

    // A fragments for the four 16-row query tiles (k-slots 8..31 = +0.0).
    bf16x8 afrag[4];
    #pragma unroll
    for (int rt = 0; rt < 4; ++rt) {
        const uint2 qw = qpack[rt * 16 + lq];
        int4 ai = { lo ? (int)qw.x : 0, lo ? (int)qw.y : 0, 0, 0 };
        afrag[rt] = __builtin_bit_cast(bf16x8, ai);
    }

    f32x4 rm[4];
    #pragma unroll
    for (int rt = 0; rt < 4; ++rt) rm[rt] = (f32x4){FINF, FINF, FINF, FINF};
    const f32x4 zero = (f32x4){0.f, 0.f, 0.f, 0.f};

    // ---- main loop: 64 col-tiles per wave ----
    #pragma unroll 4
    for (int jt = w * 64; jt < w * 64 + 64; ++jt) {
        const int j = jt * 16 + lq;
        const uint2 gw = cpack[j];          // 16 addrs, 4-way broadcast
        const float yv = cyy[j];
        // No zero-masking needed: afrag upper k-slots are +0.0.
        int4 bi = { (int)gw.x, (int)gw.y, 0, 0 };
        const bf16x8 bfrag = __builtin_bit_cast(bf16x8, bi);

        f32x4 d[4];
        #pragma unroll
        for (int rt = 0; rt < 4; ++rt)
            d[rt] = __builtin_amdgcn_mfma_f32_16x16x32_bf16(
                afrag[rt], bfrag, zero, 0, 0, 0);
        #pragma unroll
        for (int rt = 0; rt < 4; ++rt) {
            #pragma unroll
            for (int i = 0; i < 4; ++i)
                rm[rt][i] = fminf(rm[rt][i], fmaf(d[rt][i], -2.0f, yv));
        }
    }

    // ---- row-min wrap-up: min over the 16 cols held across lq lanes ----
    #pragma unroll
    for (int rt = 0; rt < 4; ++rt) {
        #pragma unroll
        for (int i = 0; i < 4; ++i) {
            float v = rm[rt][i];
            v = fminf(v, __shfl_xor(v, 1, 64));
            v = fminf(v, __shfl_xor(v, 2, 64));
            v = fminf(v, __shfl_xor(v, 4, 64));
            v = fminf(v, __shfl_xor(v, 8, 64));
            const int r = rt * 16 + grp * 4 + i;   // C/D row mapping (m89/m91)
            if (lq == 0) waveRow[w][r] = v + qxx[r];
        }
    }
    __syncthreads();

    if (w == 0) {                       // lane r owns query row r
        float v = fminf(fminf(waveRow[0][lane], waveRow[1][lane]),
                        fminf(waveRow[2][lane], waveRow[3][lane]));
        #pragma unroll
        for (int o = 32; o >= 1; o >>= 1) v += __shfl_xor(v, o, 64);
        if (lane == 0) partials[bid] = v;   // exact int sum of 64 row-mins
    }
}

// ---------------- k2: tiny fixed-order final reduce ----------------
__global__ __launch_bounds__(BLK) void chamfer_finish_kernel(
    const float* __restrict__ partials, float* __restrict__ out)
{
    __shared__ float s1[BLK];
    const int t = threadIdx.x;
    s1[t] = partials[t] + partials[t + 256];
    __syncthreads();
    for (int k = 128; k > 0; k >>= 1) {
        if (t < k) s1[t] += s1[t + k];
        __syncthreads();
    }
    if (t == 0) out[0] = s1[0] * SCALE;    // overwrite: no init needed
}

extern "C" void kernel_launch(void* const* d_in, const int* in_sizes, int n_in,
                              void* d_out, int out_size, void* d_ws, size_t ws_size,
                              hipStream_t stream)
{
    const float* preds = (const float*)d_in[0];
    const float* gts   = (const float*)d_in[1];
    float* out = (float*)d_out;
    float* partials = (float*)d_ws;        // 512 floats

    chamfer_rows_kernel<<<2 * BATCH * NTB, BLK, 0, stream>>>(
        preds, gts, partials);
    chamfer_finish_kernel<<<1, BLK, 0, stream>>>(partials, out);
}

// Round 8
// 23.289 us; speedup vs baseline: 1.7396x; 1.2773x over previous
//
#include <hip/hip_runtime.h>
#include <math.h>

// Voxelized chamfer via bf16 MFMA with algebra folded into unused K-slots:
//   vox coords are integer-valued fp32, |v| <= ~160 -> EXACT in bf16.
//   A row i : {-2qx, -2qy, -2qz, 1, 1, 0...}   (-2q = exponent shift, exact)
//   B col j : { cx,   cy,   cz, yh, yl, 0...}  (yy = yh+yl exact bf16 split)
//   MFMA   -> yy_j - 2 q_i.c_j  directly (all |vals| < 2^24: fp32-exact).
//   row-min_j (that) + xx_i = chamfer row-min. Epilogue = 1 min3 / 2 evals.
//   loss = mean(row-mins, pred->gt) + mean(row-mins, gt->pred).
//
// k1: 512 blocks = (dir, batch, 64-query tile). Stage all 4096 candidates as
//     pre-packed 16B B-frags in LDS (ALL IEEE divides here, bit-identical to
//     the reference). Each of 4 waves scans 64 col-tiles in pairs:
//     2 ds_read_b128 + 8 MFMA + 16 min3. Row-min wrap-up: 4-level shfl min,
//     +xx, cross-wave LDS min, exact int sum -> partials[bid] (1 float).
// k2: 1 block sums 512 partials (fixed-order tree, exact) and OVERWRITES
//     out[0] = sum * 2^-14. No init dispatch, no atomics, deterministic.
//
// Exactness notes: yy <= ~3*160^2 < 2^17. yh = 256*floor(yy/256): multiplier
// m <= 511 has <=9 significant bits -> yh bf16-exact; yl in [0,256) integer
// -> bf16-exact. -2q even, |.| <= 512 -> bf16-exact. Products <= ~2^17,
// MFMA fp32 accumulation of 5 terms < 2^19 -> exact.

typedef float  f32x4  __attribute__((ext_vector_type(4)));
typedef short  bf16x8 __attribute__((ext_vector_type(8)));

constexpr int NPTS  = 4096;
constexpr int BLK   = 256;
constexpr int QPB   = 64;             // query rows per block
constexpr int NTB   = NPTS / QPB;     // 64 row tiles per (dir, batch)
constexpr int BATCH = 4;
constexpr float FINF  = 3.402823466e38f;
constexpr float SCALE = 1.0f / 16384.0f;   // 1/(B*N) = 2^-14, exact

__device__ __forceinline__ float vox(float c, float off) {
    return truncf((c + off) / 0.05f);  // IEEE div: bit-matches reference
}
__device__ __forceinline__ unsigned bfbits(float v) {
    return __float_as_uint(v) >> 16;   // exact for the value classes above
}
__device__ __forceinline__ float min3(float a, float b, float c) {
    return fminf(fminf(a, b), c);      // clang fuses to v_min3_f32
}

__global__ __launch_bounds__(BLK) void chamfer_rows_kernel(
    const float* __restrict__ preds,
    const float* __restrict__ gts,
    float* __restrict__ partials)      // [512]
{
    __shared__ int4  cfrag[NPTS];      // candidate B-frags (64 KB)
    __shared__ int4  qfrag[QPB];       // query A-frags (prescaled -2, ones)
    __shared__ float qxx[QPB];         // query squared norms (exact ints)
    __shared__ float waveRow[4][QPB];

    const int t    = threadIdx.x;
    const int bid  = blockIdx.x;        // dir*256 + b*64 + tile
    const int dir  = bid >> 8;
    const int rem  = bid & 255;
    const int b    = rem >> 6;
    const int tile = rem & 63;
    const int w    = t >> 6;
    const int lane = t & 63;

    const float* __restrict__ xb = (dir ? gts : preds) + (size_t)b * NPTS * 3;
    const float* __restrict__ yb = (dir ? preds : gts) + (size_t)b * NPTS * 3;

    constexpr unsigned ONE = 0x3F80u;   // bf16 1.0

    // ---- stage candidates: voxelize, norms, split, pack B-frags ----
    for (int j = t; j < NPTS; j += BLK) {
        const float x = vox(yb[j*3+0], 3.0f);
        const float y = vox(yb[j*3+1], 3.0f);
        const float z = vox(yb[j*3+2], 1.0f);
        const float yy = fmaf(z, z, fmaf(y, y, x * x));      // exact int
        const float hi = floorf(yy * 0.00390625f) * 256.0f;  // exact
        const float lo = yy - hi;                            // in [0,256)
        cfrag[j] = make_int4(
            (int)((bfbits(y) << 16) | bfbits(x)),            // k0:cx k1:cy
            (int)((bfbits(hi) << 16) | bfbits(z)),           // k2:cz k3:yh
            (int)(bfbits(lo)),                               // k4:yl k5:0
            0);
    }
    // ---- stage this block's 64 query rows as A-frags ----
    if (t < QPB) {
        const int qi = tile * QPB + t;
        const float x = vox(xb[qi*3+0], 3.0f);
        const float y = vox(xb[qi*3+1], 3.0f);
        const float z = vox(xb[qi*3+2], 1.0f);
        qxx[t] = fmaf(z, z, fmaf(y, y, x * x));
        const float mx = -2.0f * x, my = -2.0f * y, mz = -2.0f * z; // exact
        qfrag[t] = make_int4(
            (int)((bfbits(my) << 16) | bfbits(mx)),          // k0 k1
            (int)((ONE << 16) | bfbits(mz)),                 // k2 k3:1
            (int)(ONE),                                      // k4:1 k5:0
            0);
    }
    __syncthreads();

    const int lq  = lane & 15;          // row (A) / col (B) within 16-tile
    const int grp = lane >> 4;          // lane group 0..3
    const bool lo_g = (grp == 0);       // k=0..7 carrier group

    // A fragments for the four 16-row query tiles (k-slots 8..31 = +0.0).
    bf16x8 afrag[4];
    #pragma unroll
    for (int rt = 0; rt < 4; ++rt) {
        const int4 qv = qfrag[rt * 16 + lq];
        int4 ai = { lo_g ? qv.x : 0, lo_g ? qv.y : 0, lo_g ? qv.z : 0, 0 };
        afrag[rt] = __builtin_bit_cast(bf16x8, ai);
    }

    f32x4 rm[4];
    #pragma unroll
    for (int rt = 0; rt < 4; ++rt) rm[rt] = (f32x4){FINF, FINF, FINF, FINF};
    const f32x4 zero = (f32x4){0.f, 0.f, 0.f, 0.f};

    // ---- main loop: 64 col-tiles per wave, processed in pairs ----
    #pragma unroll 2
    for (int jp = w * 32; jp < w * 32 + 32; ++jp) {
        const int jA = jp * 2, jB = jA + 1;
        const int4 bva = cfrag[jA * 16 + lq];   // b128, 4-way broadcast
        const int4 bvb = cfrag[jB * 16 + lq];
        const bf16x8 bfa = __builtin_bit_cast(bf16x8, bva);
        const bf16x8 bfb = __builtin_bit_cast(bf16x8, bvb);

        f32x4 dA[4], dB[4];
        #pragma unroll
        for (int rt = 0; rt < 4; ++rt)
            dA[rt] = __builtin_amdgcn_mfma_f32_16x16x32_bf16(
                afrag[rt], bfa, zero, 0, 0, 0);
        #pragma unroll
        for (int rt = 0; rt < 4; ++rt)
            dB[rt] = __builtin_amdgcn_mfma_f32_16x16x32_bf16(
                afrag[rt], bfb, zero, 0, 0, 0);

        #pragma unroll
        for (int rt = 0; rt < 4; ++rt) {
            #pragma unroll
            for (int i = 0; i < 4; ++i)
                rm[rt][i] = min3(rm[rt][i], dA[rt][i], dB[rt][i]);
        }
    }

    // ---- row-min wrap-up: min over the 16 cols held across lq lanes ----
    #pragma unroll
    for (int rt = 0; rt < 4; ++rt) {
        #pragma unroll
        for (int i = 0; i < 4; ++i) {
            float v = rm[rt][i];
            v = fminf(v, __shfl_xor(v, 1, 64));
            v = fminf(v, __shfl_xor(v, 2, 64));
            v = fminf(v, __shfl_xor(v, 4, 64));
            v = fminf(v, __shfl_xor(v, 8, 64));
            const int r = rt * 16 + grp * 4 + i;   // C/D row map (m89/m91)
            if (lq == 0) waveRow[w][r] = v + qxx[r];
        }
    }
    __syncthreads();

    if (w == 0) {                       // lane r owns query row r
        float v = fminf(fminf(waveRow[0][lane], waveRow[1][lane]),
                        fminf(waveRow[2][lane], waveRow[3][lane]));
        #pragma unroll
        for (int o = 32; o >= 1; o >>= 1) v += __shfl_xor(v, o, 64);
        if (lane == 0) partials[bid] = v;   // exact int sum of 64 row-mins
    }
}

// ---------------- k2: tiny fixed-order final reduce ----------------
__global__ __launch_bounds__(BLK) void chamfer_finish_kernel(
    const float* __restrict__ partials, float* __restrict__ out)
{
    __shared__ float s1[BLK];
    const int t = threadIdx.x;
    s1[t] = partials[t] + partials[t + 256];
    __syncthreads();
    for (int k = 128; k > 0; k >>= 1) {
        if (t < k) s1[t] += s1[t + k];
        __syncthreads();
    }
    if (t == 0) out[0] = s1[0] * SCALE;    // overwrite: no init needed
}

extern "C" void kernel_launch(void* const* d_in, const int* in_sizes, int n_in,
                              void* d_out, int out_size, void* d_ws, size_t ws_size,
                              hipStream_t stream)
{
    const float* preds = (const float*)d_in[0];
    const float* gts   = (const float*)d_in[1];
    float* out = (float*)d_out;
    float* partials = (float*)d_ws;        // 512 floats

    chamfer_rows_kernel<<<2 * BATCH * NTB, BLK, 0, stream>>>(
        preds, gts, partials);
    chamfer_finish_kernel<<<1, BLK, 0, stream>>>(partials, out);
}